// Round 1
// baseline (4834.673 us; speedup 1.0000x reference)
//
#include <hip/hip_runtime.h>
#include <stdint.h>

// ---------------------------------------------------------------------------
// Threefry2x32 (exact JAX semantics, 20 rounds)
// ---------------------------------------------------------------------------
__device__ __forceinline__ uint2 tf2x32(uint2 k, unsigned x0, unsigned x1) {
  unsigned ks0 = k.x, ks1 = k.y, ks2 = k.x ^ k.y ^ 0x1BD11BDAu;
  x0 += ks0; x1 += ks1;
#define TFR(d) { x0 += x1; x1 = (x1 << d) | (x1 >> (32 - d)); x1 ^= x0; }
  TFR(13) TFR(15) TFR(26) TFR(6)
  x0 += ks1; x1 += ks2 + 1u;
  TFR(17) TFR(29) TFR(16) TFR(24)
  x0 += ks2; x1 += ks0 + 2u;
  TFR(13) TFR(15) TFR(26) TFR(6)
  x0 += ks0; x1 += ks1 + 3u;
  TFR(17) TFR(29) TFR(16) TFR(24)
  x0 += ks1; x1 += ks2 + 4u;
  TFR(13) TFR(15) TFR(26) TFR(6)
  x0 += ks2; x1 += ks0 + 5u;
#undef TFR
  return make_uint2(x0, x1);
}

// uniform [0,1): JAX mapping (bits>>9)|0x3f800000 - 1.0
__device__ __forceinline__ float bits01(unsigned b) {
  return __uint_as_float((b >> 9) | 0x3f800000u) - 1.0f;
}

// XLA ErfInv32 (Giles polynomial), contraction off to match XLA's mul/add chain
__device__ __forceinline__ float erfinv_f(float x) {
#pragma clang fp contract(off)
  float w = -log1pf(-(x * x));
  float p;
  if (w < 5.0f) {
    w = w - 2.5f;
    p = 2.81022636e-08f;
    p = 3.43273939e-07f + p * w;
    p = -3.5233877e-06f + p * w;
    p = -4.39150654e-06f + p * w;
    p = 0.00021858087f + p * w;
    p = -0.00125372503f + p * w;
    p = -0.00417768164f + p * w;
    p = 0.246640727f + p * w;
    p = 1.50140941f + p * w;
  } else {
    w = sqrtf(w) - 3.0f;
    p = -0.000200214257f;
    p = 0.000100950558f + p * w;
    p = 0.00134934322f + p * w;
    p = -0.00367342844f + p * w;
    p = 0.00573950773f + p * w;
    p = -0.0076224613f + p * w;
    p = 0.00943887047f + p * w;
    p = 1.00167406f + p * w;
    p = 2.83297682f + p * w;
  }
  return p * x;
}

__device__ __forceinline__ float wredsum(float v) {
#pragma unroll
  for (int off = 32; off >= 1; off >>= 1) v += __shfl_xor(v, off, 64);
  return v;
}

__device__ __forceinline__ float digamma_f(float xf) {
  float x = xf, res = 0.0f;
  while (x < 6.0f) { res -= 1.0f / x; x += 1.0f; }
  float r = 1.0f / x, r2 = r * r;
  res += logf(x) - 0.5f * r
       - r2 * (1.0f/12.0f - r2 * (1.0f/120.0f - r2 * (1.0f/252.0f - r2 * (1.0f/240.0f))));
  return res;
}

// ---------------------------------------------------------------------------
// GEMM: C[M,128] = A[M,10000] @ W[10000,128] + bias.  64-row tile per block.
// block = 256 threads (tx 0..31 -> 4-col group, ty 0..7 -> 8-row group)
// ---------------------------------------------------------------------------
__global__ __launch_bounds__(256) void gemm_feat(const float* __restrict__ A,
                                                 const float* __restrict__ W,
                                                 const float* __restrict__ bias,
                                                 float* __restrict__ C) {
  __shared__ __align__(16) float As[64 * 32];
  __shared__ __align__(16) float Ws[32 * 128];
  const int K = 10000;
  int tid = threadIdx.x;
  int tx = tid & 31, ty = tid >> 5;
  size_t rowBase = (size_t)blockIdx.x * 64;
  float acc[8][4];
#pragma unroll
  for (int r = 0; r < 8; r++)
#pragma unroll
    for (int c = 0; c < 4; c++) acc[r][c] = 0.0f;

  for (int kc = 0; kc < K; kc += 32) {
    int rem = K - kc;  // 10000 % 32 == 16, so last chunk rem = 16
#pragma unroll
    for (int l = 0; l < 2; l++) {
      int f4 = tid + l * 256;
      int r = f4 >> 3, c4 = f4 & 7;
      float4 v = make_float4(0.f, 0.f, 0.f, 0.f);
      if (c4 * 4 < rem) v = *(const float4*)(A + (rowBase + r) * (size_t)K + kc + c4 * 4);
      *(float4*)(As + r * 32 + c4 * 4) = v;
    }
#pragma unroll
    for (int l = 0; l < 4; l++) {
      int f4 = tid + l * 256;
      int r = f4 >> 5, c4 = f4 & 31;
      float4 v = make_float4(0.f, 0.f, 0.f, 0.f);
      if (r < rem) v = *(const float4*)(W + (size_t)(kc + r) * 128 + c4 * 4);
      *(float4*)(Ws + r * 128 + c4 * 4) = v;
    }
    __syncthreads();
#pragma unroll
    for (int q = 0; q < 8; q++) {
      float bq[4][4];
#pragma unroll
      for (int j = 0; j < 4; j++) {
        float4 t4 = *(const float4*)(Ws + (q * 4 + j) * 128 + tx * 4);
        bq[j][0] = t4.x; bq[j][1] = t4.y; bq[j][2] = t4.z; bq[j][3] = t4.w;
      }
#pragma unroll
      for (int r = 0; r < 8; r++) {
        float4 t4 = *(const float4*)(As + (ty * 8 + r) * 32 + q * 4);
        float aq[4] = {t4.x, t4.y, t4.z, t4.w};
#pragma unroll
        for (int j = 0; j < 4; j++)
#pragma unroll
          for (int c = 0; c < 4; c++) acc[r][c] += aq[j] * bq[j][c];
      }
    }
    __syncthreads();
  }
#pragma unroll
  for (int r = 0; r < 8; r++) {
    size_t row = rowBase + ty * 8 + r;
    float4 o;
    o.x = acc[r][0] + bias[tx * 4 + 0];
    o.y = acc[r][1] + bias[tx * 4 + 1];
    o.z = acc[r][2] + bias[tx * 4 + 2];
    o.w = acc[r][3] + bias[tx * 4 + 3];
    *(float4*)(C + row * 128 + tx * 4) = o;
  }
}

// ---------------------------------------------------------------------------
// Layer-0 attention + aggregate + tanh.  One wave per self-row. d=128.
// ---------------------------------------------------------------------------
__global__ __launch_bounds__(64) void conv_agg(const float* __restrict__ hs,
                                               const float* __restrict__ hn,
                                               const float* __restrict__ aw,
                                               const float* __restrict__ ab,
                                               float* __restrict__ eout) {
  int b = blockIdx.x, t = threadIdx.x;
  size_t sb = (size_t)b * 128;
  float hs0 = hs[sb + t], hs1 = hs[sb + 64 + t];
  float aws0 = aw[t], aws1 = aw[64 + t], awn0 = aw[128 + t], awn1 = aw[192 + t];
  float abv = ab[0];
  float sself = wredsum(hs0 * aws0 + hs1 * aws1);
  float hv0[10], hv1[10], sg[10];
#pragma unroll
  for (int n = 0; n < 10; n++) {
    const float* hr = hn + ((size_t)b * 10 + n) * 128;
    hv0[n] = hr[t]; hv1[n] = hr[64 + t];
    float lg = sself + wredsum(hv0[n] * awn0 + hv1[n] * awn1) + abv;
    sg[n] = 1.0f / (1.0f + expf(-lg));
  }
  float m = sg[0];
#pragma unroll
  for (int n = 1; n < 10; n++) m = fmaxf(m, sg[n]);
  float e[10], se = 0.0f;
#pragma unroll
  for (int n = 0; n < 10; n++) { e[n] = expf(sg[n] - m); se += e[n]; }
  float a0 = 0.0f, a1 = 0.0f;
#pragma unroll
  for (int n = 0; n < 10; n++) {
    float wa = e[n] / se;
    a0 += wa * hv0[n]; a1 += wa * hv1[n];
  }
  eout[sb + t]      = tanhf(0.5f * hs0 + 0.5f * a0);
  eout[sb + 64 + t] = tanhf(0.5f * hs1 + 0.5f * a1);
}

// ---------------------------------------------------------------------------
// Layer-1: tiny GEMMs (K=128 -> 64 cols) + attention + identity act.
// One wave per self-row; thread t = output topic j.
// ---------------------------------------------------------------------------
__global__ __launch_bounds__(64) void layer1_k(const float* __restrict__ e0,
                                               const float* __restrict__ e1,
                                               const float* __restrict__ W1,
                                               const float* __restrict__ b1,
                                               const float* __restrict__ aw,
                                               const float* __restrict__ ab,
                                               float* __restrict__ de,
                                               float* __restrict__ att_out) {
  int b = blockIdx.x, t = threadIdx.x;
  float bt = b1[t];
  const float* er = e0 + (size_t)b * 128;
  float gs = bt;
  for (int d = 0; d < 128; d++) gs += er[d] * W1[d * 64 + t];
  float gn[10];
#pragma unroll
  for (int n = 0; n < 10; n++) {
    const float* en = e1 + ((size_t)b * 10 + n) * 128;
    float g = bt;
    for (int d = 0; d < 128; d++) g += en[d] * W1[d * 64 + t];
    gn[n] = g;
  }
  float aws = aw[t], awn = aw[64 + t], abv = ab[0];
  float sself = wredsum(gs * aws);
  float sg[10];
#pragma unroll
  for (int n = 0; n < 10; n++) {
    float lg = sself + wredsum(gn[n] * awn) + abv;
    sg[n] = 1.0f / (1.0f + expf(-lg));
  }
  float m = sg[0];
#pragma unroll
  for (int n = 1; n < 10; n++) m = fmaxf(m, sg[n]);
  float e[10], se = 0.0f;
#pragma unroll
  for (int n = 0; n < 10; n++) { e[n] = expf(sg[n] - m); se += e[n]; }
  float att[10];
#pragma unroll
  for (int n = 0; n < 10; n++) att[n] = e[n] / se;
  if (t < 10) att_out[(size_t)b * 10 + t] = att[t];
  float agg = 0.0f;
#pragma unroll
  for (int n = 0; n < 10; n++) agg += att[n] * gn[n];
  de[(size_t)b * 64 + t] = 0.5f * gs + 0.5f * agg;
}

// ---------------------------------------------------------------------------
// BatchNorm (training-mode batch stats, biased var) + softplus alpha.
// grid = 64 columns, 64 threads (4 rows each).
// ---------------------------------------------------------------------------
__global__ __launch_bounds__(64) void bnorm_k(const float* __restrict__ de,
                                              float* __restrict__ mean_out,
                                              float* __restrict__ alpha_out) {
  int j = blockIdx.x, t = threadIdx.x;
  float x[4];
#pragma unroll
  for (int r = 0; r < 4; r++) x[r] = de[(size_t)(t + r * 64) * 64 + j];
  float s = x[0] + x[1] + x[2] + x[3];
  s = wredsum(s);
  float mu = s * 0.00390625f;  // /256 exact
  float q = 0.0f;
#pragma unroll
  for (int r = 0; r < 4; r++) { float dv = x[r] - mu; q += dv * dv; }
  q = wredsum(q);
  float var = q * 0.00390625f;
  float denom = sqrtf(var + 1e-5f);
#pragma unroll
  for (int r = 0; r < 4; r++) {
    float mval = (x[r] - mu) / denom;
    size_t idx = (size_t)(t + r * 64) * 64 + j;
    mean_out[idx] = mval;
    alpha_out[idx] = fmaxf(1e-12f, logf(1.0f + expf(mval)));
  }
}

// ---------------------------------------------------------------------------
// Gamma sampling: JAX _gamma_one (Marsaglia-Tsang), partitionable threefry.
// key(42)=(0,42); kg = block(root,(0,0)); per-elem key_i = block(kg,(0,i)).
// ---------------------------------------------------------------------------
__global__ __launch_bounds__(256) void gamma_k(const float* __restrict__ alpha,
                                               float* __restrict__ gout) {
#pragma clang fp contract(off)
  int i = blockIdx.x * 256 + threadIdx.x;
  float al = alpha[i];
  float aB = al + 10.0f;
  uint2 root = make_uint2(0u, 42u);
  uint2 kg = tf2x32(root, 0u, 0u);
  uint2 key = tf2x32(kg, 0u, (unsigned)i);
  const float ot = 0.33333334f;  // f32(1/3), matches _lax_const
  float d = aB - ot;
  float c = ot / sqrtf(9.0f * d);
  float X = 0.0f, V = 1.0f, U = 2.0f;
  int guard = 0;
  while ((U >= 1.0f - 0.0331f * (X * X)) &&
         (logf(U) >= 0.5f * X + d * ((1.0f - V) + logf(V)))) {
    uint2 k0 = tf2x32(key, 0u, 0u);
    uint2 xk = tf2x32(key, 0u, 1u);
    uint2 Uk = tf2x32(key, 0u, 2u);
    key = k0;
    float x, v;
    do {
      uint2 nxt = tf2x32(xk, 0u, 0u);
      uint2 sub = tf2x32(xk, 0u, 1u);
      uint2 nb = tf2x32(sub, 0u, 0u);
      float r = bits01(nb.x ^ nb.y);
      const float lo = -0.99999994f;            // nextafter(-1,0)
      float uu = fmaxf(lo, r * 2.0f + lo);      // (hi-lo) rounds to 2.0f
      x = 1.41421356f * erfinv_f(uu);           // f32(sqrt(2)) = 0x3FB504F3
      v = 1.0f + x * c;
      xk = nxt;
    } while (v <= 0.0f);
    X = x * x;
    V = (v * v) * v;
    uint2 ubb = tf2x32(Uk, 0u, 0u);
    U = bits01(ubb.x ^ ubb.y);
    if (++guard > 200) break;
  }
  float g = d * V;
  // faithful epsilon -> gamma_tmp recompute (algebraically == g)
  float b_ = aB - ot;
  float eps = sqrtf(9.0f * aB - 3.0f) * (cbrtf(g / b_) - 1.0f);
  float t1 = 1.0f + eps / sqrtf(9.0f * b_);
  gout[i] = b_ * (t1 * t1) * t1;
}

// ---------------------------------------------------------------------------
// u-power product, gamma finalize, Dirichlet normalize.  ku = block(root,(0,1)).
// u[i,b,k] from counter i*16384 + b*64 + k (row-major flat).
// ---------------------------------------------------------------------------
__global__ __launch_bounds__(64) void topic_k(const float* __restrict__ alpha,
                                              const float* __restrict__ gtmp,
                                              float* __restrict__ out_dt) {
#pragma clang fp contract(off)
  int b = blockIdx.x, t = threadIdx.x;
  int idx = b * 64 + t;
  float al = alpha[idx];
  uint2 root = make_uint2(0u, 42u);
  uint2 ku = tf2x32(root, 0u, 1u);
  float up = 1.0f;
  for (int i2 = 0; i2 < 10; i2++) {
    uint2 bb = tf2x32(ku, 0u, (unsigned)(i2 * 16384 + idx));
    float r = bits01(bb.x ^ bb.y);
    float ex = 1.0f / (al + (float)i2);
    up = up * (powf(r, ex) + 1e-10f);
  }
  float g = up * gtmp[idx];
  float s = wredsum(g);
  out_dt[idx] = g / s;
}

// ---------------------------------------------------------------------------
// Dirichlet KL(alpha || 0.1) averaged over batch.  One block, thread = row.
// ---------------------------------------------------------------------------
__global__ __launch_bounds__(256) void kld_k(const float* __restrict__ alpha,
                                             float* __restrict__ okld) {
  int b = threadIdx.x;
  const float* ar = alpha + (size_t)b * 64;
  float sa = 0.0f;
  for (int k = 0; k < 64; k++) sa += ar[k];
  float dgs = digamma_f(sa);
  float sga = 0.0f, acc = 0.0f;
  for (int k = 0; k < 64; k++) {
    float a = ar[k];
    sga += lgammaf(a);
    acc += (a - 0.1f) * (digamma_f(a) - dgs);
  }
  float row = lgammaf(sa) - lgammaf(0.1f * 64.0f) - sga + 64.0f * lgammaf(0.1f) + acc;
  __shared__ float red[256];
  red[b] = row;
  __syncthreads();
  for (int s2 = 128; s2 > 0; s2 >>= 1) {
    if (b < s2) red[b] += red[b + s2];
    __syncthreads();
  }
  if (b == 0) okld[0] = red[0] * 0.00390625f;
}

// ---------------------------------------------------------------------------
extern "C" void kernel_launch(void* const* d_in, const int* in_sizes, int n_in,
                              void* d_out, int out_size, void* d_ws, size_t ws_size,
                              hipStream_t stream) {
  const float* feat0 = (const float*)d_in[0];
  const float* feat1 = (const float*)d_in[1];
  const float* feat2 = (const float*)d_in[2];
  const float* W0    = (const float*)d_in[3];
  const float* b0    = (const float*)d_in[4];
  const float* a0w   = (const float*)d_in[5];
  const float* a0b   = (const float*)d_in[6];
  const float* W1    = (const float*)d_in[7];
  const float* b1    = (const float*)d_in[8];
  const float* a1w   = (const float*)d_in[9];
  const float* a1b   = (const float*)d_in[10];
  float* out = (float*)d_out;
  float* ws  = (float*)d_ws;

  float* h0    = ws;                 // 256*128
  float* h1    = h0 + 32768;         // 2560*128
  float* h2    = h1 + 327680;        // 25600*128
  float* e0    = h2 + 3276800;       // 256*128
  float* e1    = e0 + 32768;         // 2560*128
  float* de    = e1 + 327680;        // 256*64
  float* alpha = de + 16384;         // 256*64
  float* gtmp  = alpha + 16384;      // 256*64

  float* out_dt   = out;             // 16384
  float* out_mean = out + 16384;     // 16384
  float* out_kld  = out + 32768;     // 1
  float* out_att  = out + 32769;     // 2560

  gemm_feat<<<4,   256, 0, stream>>>(feat0, W0, b0, h0);
  gemm_feat<<<40,  256, 0, stream>>>(feat1, W0, b0, h1);
  gemm_feat<<<400, 256, 0, stream>>>(feat2, W0, b0, h2);
  conv_agg<<<256,  64, 0, stream>>>(h0, h1, a0w, a0b, e0);
  conv_agg<<<2560, 64, 0, stream>>>(h1, h2, a0w, a0b, e1);
  layer1_k<<<256, 64, 0, stream>>>(e0, e1, W1, b1, a1w, a1b, de, out_att);
  bnorm_k<<<64, 64, 0, stream>>>(de, out_mean, alpha);
  gamma_k<<<64, 256, 0, stream>>>(alpha, gtmp);
  topic_k<<<256, 64, 0, stream>>>(alpha, gtmp, out_dt);
  kld_k<<<1, 256, 0, stream>>>(alpha, out_kld);
}

// Round 2
// 2304.492 us; speedup vs baseline: 2.0979x; 2.0979x over previous
//
#include <hip/hip_runtime.h>
#include <stdint.h>

// ---------------------------------------------------------------------------
// Threefry2x32 (exact JAX semantics, 20 rounds)
// ---------------------------------------------------------------------------
__device__ __forceinline__ uint2 tf2x32(uint2 k, unsigned x0, unsigned x1) {
  unsigned ks0 = k.x, ks1 = k.y, ks2 = k.x ^ k.y ^ 0x1BD11BDAu;
  x0 += ks0; x1 += ks1;
#define TFR(d) { x0 += x1; x1 = (x1 << d) | (x1 >> (32 - d)); x1 ^= x0; }
  TFR(13) TFR(15) TFR(26) TFR(6)
  x0 += ks1; x1 += ks2 + 1u;
  TFR(17) TFR(29) TFR(16) TFR(24)
  x0 += ks2; x1 += ks0 + 2u;
  TFR(13) TFR(15) TFR(26) TFR(6)
  x0 += ks0; x1 += ks1 + 3u;
  TFR(17) TFR(29) TFR(16) TFR(24)
  x0 += ks1; x1 += ks2 + 4u;
  TFR(13) TFR(15) TFR(26) TFR(6)
  x0 += ks2; x1 += ks0 + 5u;
#undef TFR
  return make_uint2(x0, x1);
}

// uniform [0,1): JAX mapping (bits>>9)|0x3f800000 - 1.0
__device__ __forceinline__ float bits01(unsigned b) {
  return __uint_as_float((b >> 9) | 0x3f800000u) - 1.0f;
}

// XLA ErfInv32 (Giles polynomial), contraction off to match XLA's mul/add chain
__device__ __forceinline__ float erfinv_f(float x) {
#pragma clang fp contract(off)
  float w = -log1pf(-(x * x));
  float p;
  if (w < 5.0f) {
    w = w - 2.5f;
    p = 2.81022636e-08f;
    p = 3.43273939e-07f + p * w;
    p = -3.5233877e-06f + p * w;
    p = -4.39150654e-06f + p * w;
    p = 0.00021858087f + p * w;
    p = -0.00125372503f + p * w;
    p = -0.00417768164f + p * w;
    p = 0.246640727f + p * w;
    p = 1.50140941f + p * w;
  } else {
    w = sqrtf(w) - 3.0f;
    p = -0.000200214257f;
    p = 0.000100950558f + p * w;
    p = 0.00134934322f + p * w;
    p = -0.00367342844f + p * w;
    p = 0.00573950773f + p * w;
    p = -0.0076224613f + p * w;
    p = 0.00943887047f + p * w;
    p = 1.00167406f + p * w;
    p = 2.83297682f + p * w;
  }
  return p * x;
}

__device__ __forceinline__ float wredsum(float v) {
#pragma unroll
  for (int off = 32; off >= 1; off >>= 1) v += __shfl_xor(v, off, 64);
  return v;
}

__device__ __forceinline__ float digamma_f(float xf) {
  float x = xf, res = 0.0f;
  while (x < 6.0f) { res -= 1.0f / x; x += 1.0f; }
  float r = 1.0f / x, r2 = r * r;
  res += logf(x) - 0.5f * r
       - r2 * (1.0f/12.0f - r2 * (1.0f/120.0f - r2 * (1.0f/252.0f - r2 * (1.0f/240.0f))));
  return res;
}

// ---------------------------------------------------------------------------
// Merged GEMM: one launch for feat0/feat1/feat2 @ W0 + b0 -> h_all[28416,128].
// 32-row tiles, 888 blocks, 256 threads; per-thread 4 rows x 4 cols.
// blocks 0..7 -> feat0 (256 rows), 8..87 -> feat1 (2560), 88..887 -> feat2.
// ---------------------------------------------------------------------------
__global__ __launch_bounds__(256) void gemm_all(const float* __restrict__ feat0,
                                                const float* __restrict__ feat1,
                                                const float* __restrict__ feat2,
                                                const float* __restrict__ W,
                                                const float* __restrict__ bias,
                                                float* __restrict__ C) {
  __shared__ __align__(16) float As[32 * 36];   // +4 pad per row
  __shared__ __align__(16) float Ws[32 * 128];
  const int K = 10000;
  int tid = threadIdx.x;
  int tx = tid & 31, ty = tid >> 5;           // tx: col group (4 cols), ty: row group (4 rows)
  int bid = blockIdx.x;
  const float* A;
  size_t aRow0;
  if (bid < 8)       { A = feat0; aRow0 = (size_t)bid * 32; }
  else if (bid < 88) { A = feat1; aRow0 = (size_t)(bid - 8) * 32; }
  else               { A = feat2; aRow0 = (size_t)(bid - 88) * 32; }
  size_t cRow0 = (size_t)bid * 32;

  float acc[4][4];
#pragma unroll
  for (int r = 0; r < 4; r++)
#pragma unroll
    for (int c = 0; c < 4; c++) acc[r][c] = 0.0f;

  // A-staging index: thread t covers row r=t>>3, 16B chunk c4=t&7
  int ar = tid >> 3, ac4 = tid & 7;
  const float* aBase = A + (aRow0 + ar) * (size_t)K + ac4 * 4;

  for (int kc = 0; kc < K; kc += 32) {
    int rem = K - kc;  // last chunk: rem = 16
    {
      float4 v = make_float4(0.f, 0.f, 0.f, 0.f);
      if (ac4 * 4 < rem) v = *(const float4*)(aBase + kc);
      *(float4*)(As + ar * 36 + ac4 * 4) = v;
    }
#pragma unroll
    for (int l = 0; l < 4; l++) {
      int f4 = tid + l * 256;
      int r = f4 >> 5, c4 = f4 & 31;
      float4 v = make_float4(0.f, 0.f, 0.f, 0.f);
      if (r < rem) v = *(const float4*)(W + (size_t)(kc + r) * 128 + c4 * 4);
      *(float4*)(Ws + r * 128 + c4 * 4) = v;
    }
    __syncthreads();
#pragma unroll
    for (int q = 0; q < 8; q++) {
      float bq[4][4];
#pragma unroll
      for (int j = 0; j < 4; j++) {
        float4 t4 = *(const float4*)(Ws + (q * 4 + j) * 128 + tx * 4);
        bq[j][0] = t4.x; bq[j][1] = t4.y; bq[j][2] = t4.z; bq[j][3] = t4.w;
      }
#pragma unroll
      for (int r = 0; r < 4; r++) {
        float4 t4 = *(const float4*)(As + (ty * 4 + r) * 36 + q * 4);
        float aq[4] = {t4.x, t4.y, t4.z, t4.w};
#pragma unroll
        for (int j = 0; j < 4; j++)
#pragma unroll
          for (int c = 0; c < 4; c++) acc[r][c] += aq[j] * bq[j][c];
      }
    }
    __syncthreads();
  }
#pragma unroll
  for (int r = 0; r < 4; r++) {
    size_t row = cRow0 + ty * 4 + r;
    float4 o;
    o.x = acc[r][0] + bias[tx * 4 + 0];
    o.y = acc[r][1] + bias[tx * 4 + 1];
    o.z = acc[r][2] + bias[tx * 4 + 2];
    o.w = acc[r][3] + bias[tx * 4 + 3];
    *(float4*)(C + row * 128 + tx * 4) = o;
  }
}

// ---------------------------------------------------------------------------
// Layer-0 attention + aggregate + tanh.  One wave per self-row. d=128.
// ---------------------------------------------------------------------------
__global__ __launch_bounds__(64) void conv_agg(const float* __restrict__ hs,
                                               const float* __restrict__ hn,
                                               const float* __restrict__ aw,
                                               const float* __restrict__ ab,
                                               float* __restrict__ eout) {
  int b = blockIdx.x, t = threadIdx.x;
  size_t sb = (size_t)b * 128;
  float hs0 = hs[sb + t], hs1 = hs[sb + 64 + t];
  float aws0 = aw[t], aws1 = aw[64 + t], awn0 = aw[128 + t], awn1 = aw[192 + t];
  float abv = ab[0];
  float sself = wredsum(hs0 * aws0 + hs1 * aws1);
  float hv0[10], hv1[10], sg[10];
#pragma unroll
  for (int n = 0; n < 10; n++) {
    const float* hr = hn + ((size_t)b * 10 + n) * 128;
    hv0[n] = hr[t]; hv1[n] = hr[64 + t];
    float lg = sself + wredsum(hv0[n] * awn0 + hv1[n] * awn1) + abv;
    sg[n] = 1.0f / (1.0f + expf(-lg));
  }
  float m = sg[0];
#pragma unroll
  for (int n = 1; n < 10; n++) m = fmaxf(m, sg[n]);
  float e[10], se = 0.0f;
#pragma unroll
  for (int n = 0; n < 10; n++) { e[n] = expf(sg[n] - m); se += e[n]; }
  float a0 = 0.0f, a1 = 0.0f;
#pragma unroll
  for (int n = 0; n < 10; n++) {
    float wa = e[n] / se;
    a0 += wa * hv0[n]; a1 += wa * hv1[n];
  }
  eout[sb + t]      = tanhf(0.5f * hs0 + 0.5f * a0);
  eout[sb + 64 + t] = tanhf(0.5f * hs1 + 0.5f * a1);
}

// ---------------------------------------------------------------------------
// Layer-1: tiny GEMMs (K=128 -> 64 cols) + attention + identity act.
// One wave per self-row; thread t = output topic j.
// ---------------------------------------------------------------------------
__global__ __launch_bounds__(64) void layer1_k(const float* __restrict__ e0,
                                               const float* __restrict__ e1,
                                               const float* __restrict__ W1,
                                               const float* __restrict__ b1,
                                               const float* __restrict__ aw,
                                               const float* __restrict__ ab,
                                               float* __restrict__ de,
                                               float* __restrict__ att_out) {
  int b = blockIdx.x, t = threadIdx.x;
  float bt = b1[t];
  const float* er = e0 + (size_t)b * 128;
  float gs = bt;
  for (int d = 0; d < 128; d++) gs += er[d] * W1[d * 64 + t];
  float gn[10];
#pragma unroll
  for (int n = 0; n < 10; n++) {
    const float* en = e1 + ((size_t)b * 10 + n) * 128;
    float g = bt;
    for (int d = 0; d < 128; d++) g += en[d] * W1[d * 64 + t];
    gn[n] = g;
  }
  float aws = aw[t], awn = aw[64 + t], abv = ab[0];
  float sself = wredsum(gs * aws);
  float sg[10];
#pragma unroll
  for (int n = 0; n < 10; n++) {
    float lg = sself + wredsum(gn[n] * awn) + abv;
    sg[n] = 1.0f / (1.0f + expf(-lg));
  }
  float m = sg[0];
#pragma unroll
  for (int n = 1; n < 10; n++) m = fmaxf(m, sg[n]);
  float e[10], se = 0.0f;
#pragma unroll
  for (int n = 0; n < 10; n++) { e[n] = expf(sg[n] - m); se += e[n]; }
  float att[10];
#pragma unroll
  for (int n = 0; n < 10; n++) att[n] = e[n] / se;
  if (t < 10) att_out[(size_t)b * 10 + t] = att[t];
  float agg = 0.0f;
#pragma unroll
  for (int n = 0; n < 10; n++) agg += att[n] * gn[n];
  de[(size_t)b * 64 + t] = 0.5f * gs + 0.5f * agg;
}

// ---------------------------------------------------------------------------
// BatchNorm (training-mode batch stats, biased var) + softplus alpha.
// grid = 64 columns, 64 threads (4 rows each).  Also zeroes out_kld.
// ---------------------------------------------------------------------------
__global__ __launch_bounds__(64) void bnorm_k(const float* __restrict__ de,
                                              float* __restrict__ mean_out,
                                              float* __restrict__ alpha_out,
                                              float* __restrict__ okld) {
  int j = blockIdx.x, t = threadIdx.x;
  if (j == 0 && t == 0) okld[0] = 0.0f;
  float x[4];
#pragma unroll
  for (int r = 0; r < 4; r++) x[r] = de[(size_t)(t + r * 64) * 64 + j];
  float s = x[0] + x[1] + x[2] + x[3];
  s = wredsum(s);
  float mu = s * 0.00390625f;  // /256 exact
  float q = 0.0f;
#pragma unroll
  for (int r = 0; r < 4; r++) { float dv = x[r] - mu; q += dv * dv; }
  q = wredsum(q);
  float var = q * 0.00390625f;
  float denom = sqrtf(var + 1e-5f);
#pragma unroll
  for (int r = 0; r < 4; r++) {
    float mval = (x[r] - mu) / denom;
    size_t idx = (size_t)(t + r * 64) * 64 + j;
    mean_out[idx] = mval;
    alpha_out[idx] = fmaxf(1e-12f, logf(1.0f + expf(mval)));
  }
}

// ---------------------------------------------------------------------------
// Gamma sampling: JAX _gamma_one (Marsaglia-Tsang), partitionable threefry.
// ---------------------------------------------------------------------------
__global__ __launch_bounds__(64) void gamma_k(const float* __restrict__ alpha,
                                              float* __restrict__ gout) {
#pragma clang fp contract(off)
  int i = blockIdx.x * 64 + threadIdx.x;
  float al = alpha[i];
  float aB = al + 10.0f;
  uint2 root = make_uint2(0u, 42u);
  uint2 kg = tf2x32(root, 0u, 0u);
  uint2 key = tf2x32(kg, 0u, (unsigned)i);
  const float ot = 0.33333334f;  // f32(1/3)
  float d = aB - ot;
  float c = ot / sqrtf(9.0f * d);
  float X = 0.0f, V = 1.0f, U = 2.0f;
  int guard = 0;
  while ((U >= 1.0f - 0.0331f * (X * X)) &&
         (logf(U) >= 0.5f * X + d * ((1.0f - V) + logf(V)))) {
    uint2 k0 = tf2x32(key, 0u, 0u);
    uint2 xk = tf2x32(key, 0u, 1u);
    uint2 Uk = tf2x32(key, 0u, 2u);
    key = k0;
    float x, v;
    do {
      uint2 nxt = tf2x32(xk, 0u, 0u);
      uint2 sub = tf2x32(xk, 0u, 1u);
      uint2 nb = tf2x32(sub, 0u, 0u);
      float r = bits01(nb.x ^ nb.y);
      const float lo = -0.99999994f;            // nextafter(-1,0)
      float uu = fmaxf(lo, r * 2.0f + lo);
      x = 1.41421356f * erfinv_f(uu);
      v = 1.0f + x * c;
      xk = nxt;
    } while (v <= 0.0f);
    X = x * x;
    V = (v * v) * v;
    uint2 ubb = tf2x32(Uk, 0u, 0u);
    U = bits01(ubb.x ^ ubb.y);
    if (++guard > 200) break;
  }
  float g = d * V;
  float b_ = aB - ot;
  float eps = sqrtf(9.0f * aB - 3.0f) * (cbrtf(g / b_) - 1.0f);
  float t1 = 1.0f + eps / sqrtf(9.0f * b_);
  gout[i] = b_ * (t1 * t1) * t1;
}

// ---------------------------------------------------------------------------
// u-power product, gamma finalize, Dirichlet normalize.  ku = block(root,(0,1)).
// ---------------------------------------------------------------------------
__global__ __launch_bounds__(64) void topic_k(const float* __restrict__ alpha,
                                              const float* __restrict__ gtmp,
                                              float* __restrict__ out_dt) {
#pragma clang fp contract(off)
  int b = blockIdx.x, t = threadIdx.x;
  int idx = b * 64 + t;
  float al = alpha[idx];
  uint2 root = make_uint2(0u, 42u);
  uint2 ku = tf2x32(root, 0u, 1u);
  float up = 1.0f;
  for (int i2 = 0; i2 < 10; i2++) {
    uint2 bb = tf2x32(ku, 0u, (unsigned)(i2 * 16384 + idx));
    float r = bits01(bb.x ^ bb.y);
    float ex = 1.0f / (al + (float)i2);
    up = up * (powf(r, ex) + 1e-10f);
  }
  float g = up * gtmp[idx];
  float s = wredsum(g);
  out_dt[idx] = g / s;
}

// ---------------------------------------------------------------------------
// Dirichlet KL(alpha || 0.1), one wave per row, atomicAdd of row/256.
// ---------------------------------------------------------------------------
__global__ __launch_bounds__(64) void kld_k(const float* __restrict__ alpha,
                                            float* __restrict__ okld) {
  int b = blockIdx.x, k = threadIdx.x;
  float a = alpha[(size_t)b * 64 + k];
  float sa = wredsum(a);
  float dgs = digamma_f(sa);
  float contrib = -lgammaf(a) + (a - 0.1f) * (digamma_f(a) - dgs);
  float tot = wredsum(contrib);
  if (k == 0) {
    float row = lgammaf(sa) - lgammaf(6.4f) + 64.0f * lgammaf(0.1f) + tot;
    atomicAdd(okld, row * 0.00390625f);
  }
}

// ---------------------------------------------------------------------------
extern "C" void kernel_launch(void* const* d_in, const int* in_sizes, int n_in,
                              void* d_out, int out_size, void* d_ws, size_t ws_size,
                              hipStream_t stream) {
  const float* feat0 = (const float*)d_in[0];
  const float* feat1 = (const float*)d_in[1];
  const float* feat2 = (const float*)d_in[2];
  const float* W0    = (const float*)d_in[3];
  const float* b0    = (const float*)d_in[4];
  const float* a0w   = (const float*)d_in[5];
  const float* a0b   = (const float*)d_in[6];
  const float* W1    = (const float*)d_in[7];
  const float* b1    = (const float*)d_in[8];
  const float* a1w   = (const float*)d_in[9];
  const float* a1b   = (const float*)d_in[10];
  float* out = (float*)d_out;
  float* ws  = (float*)d_ws;

  float* h_all = ws;                  // 28416*128 = 3,637,248
  float* h0    = h_all;               // rows 0..255
  float* h1    = h_all + 256 * 128;   // rows 256..2815
  float* h2    = h_all + 2816 * 128;  // rows 2816..28415
  float* e0    = h_all + 3637248;     // 256*128
  float* e1    = e0 + 32768;          // 2560*128
  float* de    = e1 + 327680;         // 256*64
  float* alpha = de + 16384;          // 256*64
  float* gtmp  = alpha + 16384;       // 256*64

  float* out_dt   = out;              // 16384
  float* out_mean = out + 16384;      // 16384
  float* out_kld  = out + 32768;      // 1
  float* out_att  = out + 32769;      // 2560

  gemm_all<<<888, 256, 0, stream>>>(feat0, feat1, feat2, W0, b0, h_all);
  conv_agg<<<256,  64, 0, stream>>>(h0, h1, a0w, a0b, e0);
  conv_agg<<<2560, 64, 0, stream>>>(h1, h2, a0w, a0b, e1);
  layer1_k<<<256, 64, 0, stream>>>(e0, e1, W1, b1, a1w, a1b, de, out_att);
  bnorm_k<<<64, 64, 0, stream>>>(de, out_mean, alpha, out_kld);
  gamma_k<<<256, 64, 0, stream>>>(alpha, gtmp);
  topic_k<<<256, 64, 0, stream>>>(alpha, gtmp, out_dt);
  kld_k<<<256, 64, 0, stream>>>(alpha, out_kld);
}